// Round 2
// baseline (97.121 us; speedup 1.0000x reference)
//
#include <hip/hip_runtime.h>
#include <hip/hip_bf16.h>

#define B_   4096
#define S_   32
#define IN_  256
#define H_   128
#define OUT_ 256
#define BM_  32    // rows per block

typedef __attribute__((ext_vector_type(8))) short bf16x8;
typedef __attribute__((ext_vector_type(4))) float f32x4;
typedef unsigned long long ull;

__device__ __forceinline__ unsigned short f2bf(float f) {
    union { float f; unsigned u; } v; v.f = f;
    unsigned r = v.u + 0x7FFFu + ((v.u >> 16) & 1u);   // round-to-nearest-even
    return (unsigned short)(r >> 16);
}

// Transpose + f32->bf16 convert for BOTH weight tensors in one launch.
// blocks [0,1024): W1 [S][256][128] -> w1t [S][128][256]
// blocks [1024,2048): W2 [S][128][256] -> w2t [S][256][128]
__global__ void transpose_cvt_both(const float* __restrict__ W1,
                                   const float* __restrict__ W2,
                                   unsigned short* __restrict__ w1t,
                                   unsigned short* __restrict__ w2t) {
    __shared__ float tile[32][33];
    int bid = blockIdx.x;
    const float* in; unsigned short* out; int R, C, rel;
    if (bid < 1024) { in = W1; out = w1t; R = IN_; C = H_;  rel = bid; }
    else            { in = W2; out = w2t; R = H_; C = OUT_; rel = bid - 1024; }
    const int tilesR = R >> 5, tilesC = C >> 5;
    const int s   = rel / (tilesR * tilesC);
    const int rem = rel % (tilesR * tilesC);
    const int tr  = rem / tilesC, tc = rem % tilesC;
    const float* ip = in + (size_t)s * R * C;
    unsigned short* op = out + (size_t)s * C * R;
    const int t  = threadIdx.x;
    const int c  = t & 31;
    const int r4 = t >> 5;            // 0..7
#pragma unroll
    for (int i = 0; i < 4; ++i) {
        int r = r4 * 4 + i;
        tile[r][c] = ip[(size_t)(tr * 32 + r) * C + tc * 32 + c];
    }
    __syncthreads();
#pragma unroll
    for (int i = 0; i < 4; ++i) {
        int orow = r4 * 4 + i;
        int ocol = c;
        op[(size_t)(tc * 32 + orow) * R + tr * 32 + ocol] = f2bf(tile[ocol][orow]);
    }
}

// Fused per-subband MLP. grid = S * (B/BM_) = 4096 (XCD-swizzled), block = 256 (4 waves).
__global__ __launch_bounds__(256, 4) void subband_fused_kernel(
        const float* __restrict__ x,
        const unsigned short* __restrict__ w1t,   // [S][H][IN] bf16
        const float* __restrict__ b1,             // [S][H]
        const unsigned short* __restrict__ w2t,   // [S][OUT][H] bf16
        const float* __restrict__ b2,             // [S][OUT]
        float* __restrict__ out) {
    __shared__ __align__(16) unsigned char lds[24576];
    unsigned char* xs = lds;            // [32 rows][512 B] bf16, XOR-swizzled
    unsigned char* hs = lds + 16384;    // [32 rows][256 B] bf16, XOR-swizzled

    // XCD-aware swizzle: 4096 blocks, 8 XCDs, 512 blocks each -> each XCD
    // serves a contiguous bid range = 4 subbands (512 KB of weights, L2-fits).
    const int rawbid = blockIdx.x;
    const int bid    = (rawbid & 7) * 512 + (rawbid >> 3);

    const int s    = bid >> 7;          // 128 row-tiles per subband
    const int b0   = (bid & 127) << 5;  // first row of this tile
    const int tid  = threadIdx.x;
    const int lane = tid & 63;
    const int w    = tid >> 6;          // wave 0..3
    const int l15  = lane & 15;
    const int l4   = lane >> 4;         // 0..3

    // ---------- stage X tile (32 x 256 f32) -> xs as bf16, swizzled ----------
    // All 8 loads issued before any convert -> single vmcnt drain.
    {
        const int c4 = tid & 63;        // float4 column index 0..63
        const int rb = tid >> 6;        // row offset 0..3
        float4 v[8];
#pragma unroll
        for (int it = 0; it < 8; ++it) {
            const int r = it * 4 + rb;
            v[it] = *(const float4*)(x + ((size_t)(b0 + r) * S_ + s) * IN_ + (c4 << 2));
        }
#pragma unroll
        for (int it = 0; it < 8; ++it) {
            const int r = it * 4 + rb;
            ull p = (ull)f2bf(v[it].x) | ((ull)f2bf(v[it].y) << 16) |
                    ((ull)f2bf(v[it].z) << 32) | ((ull)f2bf(v[it].w) << 48);
            *(ull*)(xs + r * 512 + (((c4 << 3)) ^ ((r & 7) << 4))) = p;
        }
    }
    __syncthreads();

    // ---------- layer 1: H[32][128] = relu(X @ W1 + b1) ----------
    // wave w computes columns [w*32, w*32+32)
    f32x4 acc1[2][2] = {};
    __builtin_amdgcn_s_setprio(1);
#pragma unroll
    for (int kk = 0; kk < 8; ++kk) {
        const int kb = kk * 32 + l4 * 8;       // k element offset for this lane
        bf16x8 a[2];
#pragma unroll
        for (int rt = 0; rt < 2; ++rt) {
            const int r = rt * 16 + l15;
            a[rt] = *(const bf16x8*)(xs + r * 512 + ((kb * 2) ^ ((r & 7) << 4)));
        }
        bf16x8 bb[2];
#pragma unroll
        for (int ct = 0; ct < 2; ++ct) {
            const int n = (w << 5) + ct * 16 + l15;
            bb[ct] = *(const bf16x8*)(w1t + (size_t)(s * H_ + n) * IN_ + kb);
        }
#pragma unroll
        for (int rt = 0; rt < 2; ++rt)
#pragma unroll
            for (int ct = 0; ct < 2; ++ct)
                acc1[rt][ct] = __builtin_amdgcn_mfma_f32_16x16x32_bf16(a[rt], bb[ct], acc1[rt][ct], 0, 0, 0);
    }
    __builtin_amdgcn_s_setprio(0);
    // bias + relu -> hs (bf16, swizzled). C/D layout: col = l15, row = l4*4 + i.
    {
        float bias1[2];
        bias1[0] = b1[s * H_ + (w << 5) + l15];
        bias1[1] = b1[s * H_ + (w << 5) + 16 + l15];
#pragma unroll
        for (int rt = 0; rt < 2; ++rt)
#pragma unroll
            for (int ct = 0; ct < 2; ++ct)
#pragma unroll
                for (int i = 0; i < 4; ++i) {
                    float v = acc1[rt][ct][i] + bias1[ct];
                    v = fmaxf(v, 0.0f);
                    const int r = rt * 16 + l4 * 4 + i;
                    const int n = (w << 5) + ct * 16 + l15;
                    *(unsigned short*)(hs + r * 256 + ((n * 2) ^ ((r & 7) << 4))) = f2bf(v);
                }
    }
    __syncthreads();

    // ---------- layer 2: OUT[32][256] = H @ W2 + b2 ----------
    // wave w computes columns [w*64, w*64+64)
    f32x4 acc2[2][4] = {};
    __builtin_amdgcn_s_setprio(1);
#pragma unroll
    for (int kk = 0; kk < 4; ++kk) {
        const int kb = kk * 32 + l4 * 8;
        bf16x8 a[2];
#pragma unroll
        for (int rt = 0; rt < 2; ++rt) {
            const int r = rt * 16 + l15;
            a[rt] = *(const bf16x8*)(hs + r * 256 + ((kb * 2) ^ ((r & 7) << 4)));
        }
        bf16x8 bb[4];
#pragma unroll
        for (int ct = 0; ct < 4; ++ct) {
            const int n = (w << 6) + ct * 16 + l15;
            bb[ct] = *(const bf16x8*)(w2t + (size_t)(s * OUT_ + n) * H_ + kb);
        }
#pragma unroll
        for (int rt = 0; rt < 2; ++rt)
#pragma unroll
            for (int ct = 0; ct < 4; ++ct)
                acc2[rt][ct] = __builtin_amdgcn_mfma_f32_16x16x32_bf16(a[rt], bb[ct], acc2[rt][ct], 0, 0, 0);
    }
    __builtin_amdgcn_s_setprio(0);
    // bias + non-temporal f32 stores (don't let the 132 MB write stream evict x from L3)
    {
        float bias2[4];
#pragma unroll
        for (int ct = 0; ct < 4; ++ct)
            bias2[ct] = b2[s * OUT_ + (w << 6) + ct * 16 + l15];
#pragma unroll
        for (int rt = 0; rt < 2; ++rt)
#pragma unroll
            for (int ct = 0; ct < 4; ++ct)
#pragma unroll
                for (int i = 0; i < 4; ++i) {
                    const int r = b0 + rt * 16 + l4 * 4 + i;
                    const int n = (w << 6) + ct * 16 + l15;
                    __builtin_nontemporal_store(acc2[rt][ct][i] + bias2[ct],
                                                out + ((size_t)r * S_ + s) * OUT_ + n);
                }
    }
}

extern "C" void kernel_launch(void* const* d_in, const int* in_sizes, int n_in,
                              void* d_out, int out_size, void* d_ws, size_t ws_size,
                              hipStream_t stream) {
    const float* x  = (const float*)d_in[0];
    const float* W1 = (const float*)d_in[1];
    const float* b1 = (const float*)d_in[2];
    const float* W2 = (const float*)d_in[3];
    const float* b2 = (const float*)d_in[4];
    float* out = (float*)d_out;

    unsigned short* w1t = (unsigned short*)d_ws;                 // [S][H][IN]  bf16: 2 MiB
    unsigned short* w2t = w1t + (size_t)S_ * H_ * IN_;           // [S][OUT][H] bf16: 2 MiB

    transpose_cvt_both<<<2048, 256, 0, stream>>>(W1, W2, w1t, w2t);
    subband_fused_kernel<<<S_ * (B_ / BM_), 256, 0, stream>>>(x, w1t, b1, w2t, b2, out);
}